// Round 1
// baseline (9033.241 us; speedup 1.0000x reference)
//
#include <hip/hip_runtime.h>
#include <hip/hip_bf16.h>
#include <stdint.h>

#define BSZ 512
#define TT  256
#define IIN 64
#define HH  512
#define G4  2048
#define NSTEPS 10

typedef short bf16x8 __attribute__((ext_vector_type(8)));
typedef float f32x4  __attribute__((ext_vector_type(4)));

__device__ __forceinline__ unsigned short f2bf(float f){
  union { float f; uint32_t u; } v; v.f = f;
  uint32_t u = v.u;
  uint32_t r = (u + 0x7fffu + ((u >> 16) & 1u)) >> 16;
  return (unsigned short)r;
}
__device__ __forceinline__ float bf2f(unsigned short h){
  union { uint32_t u; float f; } v; v.u = ((uint32_t)h) << 16;
  return v.f;
}
__device__ __forceinline__ float sigf(float x){ return 1.0f/(1.0f+__expf(-x)); }
__device__ __forceinline__ float tanhfast(float x){ return 1.0f - 2.0f/(__expf(2.0f*x)+1.0f); }

// ---------------------------------------------------------------------------
// Fused LSTM cell step for a 64-batch x (4 gates x 16 cols) tile.
// gates = [A1 | A2] @ [W1 | W2]^T + bias  via bf16x3 MFMA (hi*hi+hi*lo+lo*hi)
// then pointwise LSTM update of c and h.
// Grid mapping: wg in [0,256): btile = wg>>5 (8 tiles of 64 rows),
//               ct = wg&31 (16 gate-cols each, j0 = ct*16).
// ---------------------------------------------------------------------------
__device__ void cell_body(int wg,
    const float* __restrict__ A1, long a1s, int k1c,
    const unsigned short* __restrict__ W1h, const unsigned short* __restrict__ W1l,
    const float* __restrict__ A2,
    const unsigned short* __restrict__ W2h, const unsigned short* __restrict__ W2l,
    const float* __restrict__ bias,
    float* __restrict__ cbuf, float* __restrict__ hout)
{
  __shared__ unsigned short sAh[64*40];
  __shared__ unsigned short sAl[64*40];
  __shared__ unsigned short sBh[64*40];
  __shared__ unsigned short sBl[64*40];
  __shared__ float sG[4*64*16];

  const int tid = threadIdx.x;
  const int btile = wg >> 5;
  const int ct = wg & 31;
  const int b0 = btile * 64;
  const int j0 = ct * 16;
  const int g  = tid >> 6;      // wave id == gate id
  const int l  = tid & 63;
  const int lr = l & 15;
  const int lk = (l >> 4) * 8;

  const int r  = tid >> 2;          // 0..63 staging row
  const int c8 = (tid & 3) * 8;     // 0,8,16,24 staging col
  const int w1len = k1c * 32;
  const int qn = (r >> 4) * 512 + j0 + (r & 15);  // W row (gate-major) staged by this thread

  f32x4 acc[4];
  {
    float bv = bias[g*512 + j0 + lr];
    f32x4 ini = {bv, bv, bv, bv};
    #pragma unroll
    for (int m = 0; m < 4; ++m) acc[m] = ini;
  }

  const int nch = k1c + 16;   // 32-wide K chunks
  for (int kc = 0; kc < nch; ++kc){
    // ---- stage A (64 x 32 f32 -> hi/lo bf16) ----
    const float* asrc;
    if (kc < k1c) asrc = A1 + (long)(b0 + r) * a1s + kc*32 + c8;
    else          asrc = A2 + ((long)(b0 + r) << 9) + ((kc - k1c)*32 + c8);
    f32x4 v0 = *(const f32x4*)asrc;
    f32x4 v1 = *(const f32x4*)(asrc + 4);
    union { unsigned short u[8]; bf16x8 v; } hi, lo;
    #pragma unroll
    for (int i = 0; i < 4; ++i){
      float f = v0[i]; unsigned short h = f2bf(f);
      hi.u[i] = h; lo.u[i] = f2bf(f - bf2f(h));
    }
    #pragma unroll
    for (int i = 0; i < 4; ++i){
      float f = v1[i]; unsigned short h = f2bf(f);
      hi.u[4+i] = h; lo.u[4+i] = f2bf(f - bf2f(h));
    }
    *(bf16x8*)&sAh[r*40 + c8] = hi.v;
    *(bf16x8*)&sAl[r*40 + c8] = lo.v;

    // ---- stage B (64 W-rows x 32 k, already-split bf16) ----
    {
      long woff; const unsigned short *wh, *wl;
      if (kc < k1c){ woff = (long)qn * w1len + kc*32 + c8; wh = W1h; wl = W1l; }
      else         { woff = ((long)qn << 9) + (kc - k1c)*32 + c8; wh = W2h; wl = W2l; }
      *(bf16x8*)&sBh[r*40 + c8] = *(const bf16x8*)&wh[woff];
      *(bf16x8*)&sBl[r*40 + c8] = *(const bf16x8*)&wl[woff];
    }
    __syncthreads();

    // ---- fragments + MFMA (bf16x3) ----
    bf16x8 bh = *(const bf16x8*)&sBh[(g*16 + lr)*40 + lk];
    bf16x8 bl = *(const bf16x8*)&sBl[(g*16 + lr)*40 + lk];
    #pragma unroll
    for (int m = 0; m < 4; ++m){
      bf16x8 ah = *(const bf16x8*)&sAh[(m*16 + lr)*40 + lk];
      bf16x8 al = *(const bf16x8*)&sAl[(m*16 + lr)*40 + lk];
      acc[m] = __builtin_amdgcn_mfma_f32_16x16x32_bf16(ah, bh, acc[m], 0, 0, 0);
      acc[m] = __builtin_amdgcn_mfma_f32_16x16x32_bf16(ah, bl, acc[m], 0, 0, 0);
      acc[m] = __builtin_amdgcn_mfma_f32_16x16x32_bf16(al, bh, acc[m], 0, 0, 0);
    }
    __syncthreads();
  }

  // ---- epilogue: exchange gates through LDS, pointwise LSTM ----
  #pragma unroll
  for (int m = 0; m < 4; ++m){
    int rowb = m*16 + (l >> 4)*4;
    #pragma unroll
    for (int q = 0; q < 4; ++q)
      sG[(g*64 + rowb + q)*16 + lr] = acc[m][q];
  }
  __syncthreads();
  {
    int e0 = tid * 4;
    int row = e0 >> 4;
    int col0 = e0 & 15;
    #pragma unroll
    for (int q = 0; q < 4; ++q){
      int col = col0 + q;
      float gi = sG[(0*64+row)*16 + col];
      float gf = sG[(1*64+row)*16 + col];
      float gg = sG[(2*64+row)*16 + col];
      float go = sG[(3*64+row)*16 + col];
      long idx = ((long)(b0+row) << 9) + j0 + col;
      float cold = cbuf[idx];
      float cn = sigf(gf)*cold + sigf(gi)*tanhfast(gg);
      cbuf[idx] = cn;
      hout[idx] = sigf(go)*tanhfast(cn);
    }
  }
}

// ---- encoder wavefront: L0(t=s) and L1(t=s-1) in one launch (512 WGs) ----
__global__ __launch_bounds__(256, 2)
void enc_step(const float* __restrict__ x,
              const unsigned short* Wih0h, const unsigned short* Wih0l,
              const unsigned short* Whh0h, const unsigned short* Whh0l,
              const float* b0v,
              const unsigned short* Wih1h, const unsigned short* Wih1l,
              const unsigned short* Whh1h, const unsigned short* Whh1l,
              const float* b1v,
              float* h0a, float* h0b, float* h1a, float* h1b,
              float* c0, float* c1, int s)
{
  int role = blockIdx.x >> 8;
  int wg   = blockIdx.x & 255;
  int rp = (s + 1) & 1;
  int wp = s & 1;
  const float* h0r = rp ? h0b : h0a;
  float*       h0w = wp ? h0b : h0a;
  const float* h1r = rp ? h1b : h1a;
  float*       h1w = wp ? h1b : h1a;

  if (role == 0){
    if (s >= TT) return;
    cell_body(wg, x + (long)s*IIN, (long)TT*IIN, 2,
              Wih0h, Wih0l, h0r, Whh0h, Whh0l, b0v, c0, h0w);
  } else {
    if (s < 1) return;
    cell_body(wg, h0r, (long)HH, 16,
              Wih1h, Wih1l, h1r, Whh1h, Whh1l, b1v, c1, h1w);
  }
}

// ---- single cell (decoder) ----
__global__ __launch_bounds__(256, 2)
void dec_cell(const float* A1, long a1s, int k1c,
              const unsigned short* W1h, const unsigned short* W1l,
              const float* A2,
              const unsigned short* W2h, const unsigned short* W2l,
              const float* bias, float* cbuf, float* hout)
{
  cell_body(blockIdx.x, A1, a1s, k1c, W1h, W1l, A2, W2h, W2l, bias, cbuf, hout);
}

// ---- output projection: out = h1 @ W_lin^T + b_lin  (512x64, K=512) ----
__global__ __launch_bounds__(256)
void lin_kernel(const float* __restrict__ h1, const float* __restrict__ Wlin,
                const float* __restrict__ blin, float* __restrict__ out)
{
  int gt = blockIdx.x * 256 + threadIdx.x;
  int b = gt >> 6;
  int i = gt & 63;
  const float* hr = h1 + ((long)b << 9);
  const float* wr = Wlin + ((long)i << 9);
  float s = 0.f;
  #pragma unroll 4
  for (int k = 0; k < HH; k += 4){
    f32x4 hv = *(const f32x4*)(hr + k);
    f32x4 wv = *(const f32x4*)(wr + k);
    s += hv[0]*wv[0] + hv[1]*wv[1] + hv[2]*wv[2] + hv[3]*wv[3];
  }
  out[(long)b * (NSTEPS*IIN) + i] = s + blin[i];
}

// ---- prep kernels ----
__global__ void bias_kernel(const float* a, const float* b, float* o){
  int i = blockIdx.x * 256 + threadIdx.x;
  if (i < G4) o[i] = a[i] + b[i];
}
__global__ void split_kernel(const float* __restrict__ src,
                             unsigned short* __restrict__ hi,
                             unsigned short* __restrict__ lo, int n){
  int i = blockIdx.x * 256 + threadIdx.x;
  if (i < n){
    float f = src[i];
    unsigned short h = f2bf(f);
    hi[i] = h;
    lo[i] = f2bf(f - bf2f(h));
  }
}

extern "C" void kernel_launch(void* const* d_in, const int* in_sizes, int n_in,
                              void* d_out, int out_size, void* d_ws, size_t ws_size,
                              hipStream_t stream)
{
  const float* x     = (const float*)d_in[0];
  const float* W_ih0 = (const float*)d_in[1];
  const float* W_hh0 = (const float*)d_in[2];
  const float* b_ih0 = (const float*)d_in[3];
  const float* b_hh0 = (const float*)d_in[4];
  const float* W_ih1 = (const float*)d_in[5];
  const float* W_hh1 = (const float*)d_in[6];
  const float* b_ih1 = (const float*)d_in[7];
  const float* b_hh1 = (const float*)d_in[8];
  const float* W_lin = (const float*)d_in[9];
  const float* b_lin = (const float*)d_in[10];
  float* out = (float*)d_out;

  char* ws = (char*)d_ws;
  size_t off = 0;
  auto alloc = [&](size_t bytes){ size_t o = off; off += (bytes + 255) & ~(size_t)255; return o; };

  float* b0v = (float*)(ws + alloc(G4*4));
  float* b1v = (float*)(ws + alloc(G4*4));
  unsigned short* Wih0h = (unsigned short*)(ws + alloc((size_t)G4*IIN*2));
  unsigned short* Wih0l = (unsigned short*)(ws + alloc((size_t)G4*IIN*2));
  unsigned short* Whh0h = (unsigned short*)(ws + alloc((size_t)G4*HH*2));
  unsigned short* Whh0l = (unsigned short*)(ws + alloc((size_t)G4*HH*2));
  unsigned short* Wih1h = (unsigned short*)(ws + alloc((size_t)G4*HH*2));
  unsigned short* Wih1l = (unsigned short*)(ws + alloc((size_t)G4*HH*2));
  unsigned short* Whh1h = (unsigned short*)(ws + alloc((size_t)G4*HH*2));
  unsigned short* Whh1l = (unsigned short*)(ws + alloc((size_t)G4*HH*2));
  const size_t BH = (size_t)BSZ * HH;
  float* states = (float*)(ws + alloc(6 * BH * 4));
  float* h0a = states;
  float* h0b = states + BH;
  float* h1a = states + 2*BH;
  float* h1b = states + 3*BH;
  float* c0  = states + 4*BH;
  float* c1  = states + 5*BH;

  // ---- prep ----
  bias_kernel<<<(G4+255)/256, 256, 0, stream>>>(b_ih0, b_hh0, b0v);
  bias_kernel<<<(G4+255)/256, 256, 0, stream>>>(b_ih1, b_hh1, b1v);
  {
    int n0 = G4*IIN, n1 = G4*HH;
    split_kernel<<<(n0+255)/256, 256, 0, stream>>>(W_ih0, Wih0h, Wih0l, n0);
    split_kernel<<<(n1+255)/256, 256, 0, stream>>>(W_hh0, Whh0h, Whh0l, n1);
    split_kernel<<<(n1+255)/256, 256, 0, stream>>>(W_ih1, Wih1h, Wih1l, n1);
    split_kernel<<<(n1+255)/256, 256, 0, stream>>>(W_hh1, Whh1h, Whh1l, n1);
  }
  hipMemsetAsync(states, 0, 6 * BH * 4, stream);

  // ---- encoder: 257 diagonal wavefronts ----
  for (int s = 0; s <= TT; ++s){
    enc_step<<<512, 256, 0, stream>>>(x,
        Wih0h, Wih0l, Whh0h, Whh0l, b0v,
        Wih1h, Wih1l, Whh1h, Whh1l, b1v,
        h0a, h0b, h1a, h1b, c0, c1, s);
  }

  // encoder finals: h0 written at s=255 (parity 1 -> h0b); h1 at s=256 (parity 0 -> h1a)
  float* h0_cur = h0b; float* h0_alt = h0a;
  float* h1_cur = h1a; float* h1_alt = h1b;

  // ---- decoder: 10 autoregressive steps ----
  for (int s = 0; s < NSTEPS; ++s){
    const float* cur; long cs;
    if (s == 0){ cur = x + (long)(TT-1)*IIN; cs = (long)TT*IIN; }
    else       { cur = out + (long)(s-1)*IIN; cs = (long)NSTEPS*IIN; }

    dec_cell<<<256, 256, 0, stream>>>(cur, cs, 2, Wih0h, Wih0l,
                                      h0_cur, Whh0h, Whh0l, b0v, c0, h0_alt);
    { float* t = h0_cur; h0_cur = h0_alt; h0_alt = t; }

    dec_cell<<<256, 256, 0, stream>>>(h0_cur, (long)HH, 16, Wih1h, Wih1l,
                                      h1_cur, Whh1h, Whh1l, b1v, c1, h1_alt);
    { float* t = h1_cur; h1_cur = h1_alt; h1_alt = t; }

    lin_kernel<<<128, 256, 0, stream>>>(h1_cur, W_lin, b_lin, out + (long)s*IIN);
  }
}